// Round 17
// baseline (537.439 us; speedup 1.0000x reference)
//
#include <hip/hip_runtime.h>
#include <hip/hip_bf16.h>

#define TOKS 16384
#define HID  4096
#define NEXP 64
#define EPS  1e-4f

// ===== ws layout (floats) =====
// [0..63] prob sums | [64..127] argmax counts | int@[128] flag count |
// ints [192..192+16384) flag list | [16576) Bpack (1 MB) | sink @ 64M floats
#define WS_FLAGCNT  128
#define WS_FLAGLIST 192
#define WS_BPACK    16576
#define WS_SINK     (1 << 26)

typedef __attribute__((ext_vector_type(8))) short short8_t;
typedef __attribute__((ext_vector_type(4))) float f32x4;

static __device__ __forceinline__ unsigned short f2bf_rn(float x) {
    unsigned u = __builtin_bit_cast(unsigned, x);
    u = (u + 0x7fffu + ((u >> 16) & 1u)) >> 16;
    return (unsigned short)u;
}
static __device__ __forceinline__ float bf2f(unsigned short h) {
    return __builtin_bit_cast(float, (unsigned)h << 16);
}
static __device__ __forceinline__ void gl2lds16(const void* g, void* l) {
    __builtin_amdgcn_global_load_lds(
        (const __attribute__((address_space(1))) unsigned int*)g,
        (__attribute__((address_space(3))) unsigned int*)l, 16, 0, 0);
}

// ---------- prep ----------
__global__ void moe_prep(const float* __restrict__ W, unsigned short* __restrict__ Bpk,
                         float* __restrict__ wsf) {
    const int idx = blockIdx.x * blockDim.x + threadIdx.x;
    if (idx < 192) wsf[idx] = 0.0f;
    if (idx >= NEXP * HID) return;
    const int n = idx >> 12;
    const int k = idx & 4095;
    const float w = W[idx];
    const unsigned short hi = f2bf_rn(w);
    const unsigned short lo = f2bf_rn(w - bf2f(hi));
    const int kt   = k >> 5;
    const int nt   = n >> 4;
    const int lane = (n & 15) | (((k >> 3) & 3) << 4);
    const int j    = k & 7;
    const int dst  = (((kt << 2) + nt) << 10) + (lane << 3) + j;
    Bpk[dst]       = hi;
    Bpk[dst + 512] = lo;
}

// common staging macro pieces (R12 geometry: 256 blocks x 512 thr, 4-deep bufs)
#define STAGE_BODY(bf, ss)                                                             \
    {                                                                                  \
        const int k0_ = (ss) << 6;                                                     \
        _Pragma("unroll")                                                              \
        for (int i = 0; i < 2; ++i) {                                                  \
            const int rg = (w << 3) + (i << 2) + g;                                    \
            const int ck = (lane & 15) ^ (rg & 15);                                    \
            gl2lds16(X + (size_t)(tok0 + rg) * HID + k0_ + (ck << 2),                  \
                     (void*)&xbuf[bf][(w << 3) + (i << 2)][0]);                        \
        }                                                                              \
        _Pragma("unroll")                                                              \
        for (int j = 0; j < 2; ++j) {                                                  \
            const int c1k = (w << 1) + j;                                              \
            gl2lds16((const char*)Bpk + ((size_t)(ss) << 14) + (c1k << 10) + (lane << 4), \
                     (void*)((char*)&bbuf[bf][0] + (c1k << 10)));                      \
        }                                                                              \
    }

// ---------- PROBE: memory skeleton ONLY, x8 repeats ----------
// Exact R12 staging structure (gl_lds, vmcnt(8), s_barrier, 4-deep, dist 2),
// zero compute. dur/8 = per-loop cost of the pure staging path.
__global__ __launch_bounds__(512, 1)
void moe_probe_stage(const float* __restrict__ X, const unsigned short* __restrict__ Bpk,
                     float* __restrict__ sink) {
    __shared__ __align__(16) float xbuf[4][64][64];
    __shared__ __align__(16) unsigned short bbuf[4][8192];
    const int tid  = threadIdx.x;
    const int lane = tid & 63;
    const int w    = tid >> 6;
    const int g    = lane >> 4;
    const int tok0 = blockIdx.x * 64;

    STAGE_BODY(0, 0);
    STAGE_BODY(1, 1);
    for (int rep = 0; rep < 8; ++rep) {
        for (int s = 0; s < 64; ++s) {
            const int ss = (s + 2 < 64) ? (s + 2) : 63;
            STAGE_BODY((s + 2) & 3, ss);
            asm volatile("s_waitcnt vmcnt(8)" ::: "memory");
            __builtin_amdgcn_s_barrier();
            __builtin_amdgcn_sched_barrier(0);
        }
    }
    asm volatile("s_waitcnt vmcnt(0)" ::: "memory");
    __syncthreads();
    if (tid == 0)
        sink[blockIdx.x] = xbuf[0][0][0] + (float)bbuf[0][0];   // keep LDS live
}

// ---------- fused: R12-proven pipelined MFMA GEMM + softmax + bitonic top-8 ----------
__global__ __launch_bounds__(512, 1)
void moe_fused(const float* __restrict__ X, const unsigned short* __restrict__ Bpk,
               float* __restrict__ out, float* __restrict__ wsf) {
    __shared__ __align__(16) float xbuf[4][64][64];
    __shared__ __align__(16) unsigned short bbuf[4][8192];
    float (*L)[68] = (float (*)[68])&xbuf[0][0][0];

    const int tid  = threadIdx.x;
    const int lane = tid & 63;
    const int w    = tid >> 6;
    const int mt   = w & 3;
    const int nh   = w >> 2;
    const int g    = lane >> 4;
    const int tok0 = blockIdx.x * 64;

    f32x4 acc[2];
    acc[0] = (f32x4){0.f, 0.f, 0.f, 0.f};
    acc[1] = (f32x4){0.f, 0.f, 0.f, 0.f};

    STAGE_BODY(0, 0);
    STAGE_BODY(1, 1);

    const int tr  = (mt << 4) + (lane & 15);
    const int rsw = lane & 15;

    for (int s = 0; s < 64; ++s) {
        const int cur = s & 3;
        {
            const int ss = (s + 2 < 64) ? (s + 2) : 63;
            STAGE_BODY((s + 2) & 3, ss);
        }
        asm volatile("s_waitcnt vmcnt(8)" ::: "memory");
        __builtin_amdgcn_s_barrier();
        __builtin_amdgcn_sched_barrier(0);

        const char* ab = (const char*)&xbuf[cur][tr][0];
        const char* bb = (const char*)&bbuf[cur][0];
        #pragma unroll
        for (int ktl = 0; ktl < 2; ++ktl) {
            const int cl = (ktl << 3) + (g << 1);
            const float4 a0 = *(const float4*)(ab + ((cl ^ rsw) << 4));
            const float4 a1 = *(const float4*)(ab + (((cl + 1) ^ rsw) << 4));
            const float xv[8] = {a0.x, a0.y, a0.z, a0.w, a1.x, a1.y, a1.z, a1.w};
            short8_t ah, al;
            #pragma unroll
            for (int j = 0; j < 8; ++j) {
                const unsigned u = __builtin_bit_cast(unsigned, xv[j]);
                ah[j] = (short)(u >> 16);
                const float hif = __builtin_bit_cast(float, u & 0xFFFF0000u);
                al[j] = (short)(__builtin_bit_cast(unsigned, xv[j] - hif) >> 16);
            }
            #pragma unroll
            for (int ntl = 0; ntl < 2; ++ntl) {
                const char* bp = bb + (((ktl << 2) + (nh << 1) + ntl) << 11) + (lane << 4);
                const short8_t bh = *(const short8_t*)bp;
                const short8_t bl = *(const short8_t*)(bp + 1024);
                acc[ntl] = __builtin_amdgcn_mfma_f32_16x16x32_bf16(ah, bh, acc[ntl], 0, 0, 0);
                acc[ntl] = __builtin_amdgcn_mfma_f32_16x16x32_bf16(al, bh, acc[ntl], 0, 0, 0);
                acc[ntl] = __builtin_amdgcn_mfma_f32_16x16x32_bf16(ah, bl, acc[ntl], 0, 0, 0);
            }
        }
    }
    asm volatile("s_waitcnt vmcnt(0)" ::: "memory");
    __syncthreads();

    #pragma unroll
    for (int ntl = 0; ntl < 2; ++ntl)
        #pragma unroll
        for (int r = 0; r < 4; ++r)
            L[(mt << 4) + (g << 2) + r][(nh << 5) + (ntl << 4) + (lane & 15)] = acc[ntl][r];
    __syncthreads();

    float* outIdx = out;
    float* outW   = out + TOKS * 8;
    int* flagcnt  = (int*)wsf + WS_FLAGCNT;
    int* flaglist = (int*)wsf + WS_FLAGLIST;

    float rp = 0.f;
    #pragma unroll
    for (int tt = 0; tt < 8; ++tt) {
        const int tl = (w << 3) + tt;
        const float lg = L[tl][lane];

        float v = lg; int idx = lane;
        #pragma unroll
        for (int size = 2; size <= 64; size <<= 1) {
            #pragma unroll
            for (int str = size >> 1; str > 0; str >>= 1) {
                const float ov = __shfl_xor(v, str, 64);
                const int   oi = __shfl_xor(idx, str, 64);
                const bool pb = (ov > v) || (ov == v && oi < idx);
                const bool keepFirst = ((lane & str) == 0) == ((lane & size) == 0);
                if (pb == keepFirst) { v = ov; idx = oi; }
            }
        }

        const float m = __shfl(v, 0, 64);
        const float p = __expf(lg - m);
        float sdenom = p;
        #pragma unroll
        for (int o = 32; o; o >>= 1) sdenom += __shfl_xor(sdenom, o, 64);
        const float inv_s = 1.0f / sdenom;
        rp += p * inv_s;

        const float wkv = __expf(v - m) * inv_s;
        float d8 = (lane < 8) ? wkv : 0.f;
        #pragma unroll
        for (int o = 1; o < 8; o <<= 1) d8 += __shfl_xor(d8, o, 64);
        const float invd = 1.0f / (d8 + 1e-20f);
        const float nv = __shfl_down(v, 1, 64);
        const bool flg = __any(lane < 8 && (v - nv) < EPS);

        const int gtok = tok0 + tl;
        if (lane < 8) {
            outIdx[(size_t)gtok * 8 + lane] = (float)idx;
            outW[(size_t)gtok * 8 + lane]   = wkv * invd;
        }
        if (lane == 0) {
            atomicAdd(&wsf[NEXP + idx], 1.0f);
            if (flg) {
                const int pos = atomicAdd(flagcnt, 1);
                if (pos < TOKS) flaglist[pos] = gtok;
            }
        }
    }
    atomicAdd(&wsf[lane], rp);
}

// ---------- exact fp64 redo for flagged tokens ----------
__global__ __launch_bounds__(256, 2)
void moe_fix(const float* __restrict__ X, const float* __restrict__ W,
             float* __restrict__ out, float* __restrict__ wsf) {
    __shared__ double red[256];
    const int tid = threadIdx.x;
    const int e   = tid & 63;
    const int kc  = tid >> 6;
    const int nf  = min(*((int*)wsf + WS_FLAGCNT), TOKS);
    const int* flaglist = (const int*)wsf + WS_FLAGLIST;
    float* outIdx = out;
    float* outW   = out + TOKS * 8;

    for (int fi = blockIdx.x; fi < nf; fi += gridDim.x) {
        const int tok = flaglist[fi];
        const float* xrow = X + (size_t)tok * HID + kc * 1024;
        const float* wrow = W + (size_t)e  * HID + kc * 1024;
        double part = 0.0;
        for (int j = 0; j < 1024; j += 4) {
            const float4 xv = *(const float4*)(xrow + j);
            const float4 wv = *(const float4*)(wrow + j);
            part = fma((double)xv.x, (double)wv.x, part);
            part = fma((double)xv.y, (double)wv.y, part);
            part = fma((double)xv.z, (double)wv.z, part);
            part = fma((double)xv.w, (double)wv.w, part);
        }
        red[tid] = part;
        __syncthreads();
        if (tid < 64) {
            const double lg = ((red[tid] + red[64 + tid]) + red[128 + tid]) + red[192 + tid];
            const float lgf = (float)lg;
            float m = lgf;
            #pragma unroll
            for (int o = 32; o; o >>= 1) m = fmaxf(m, __shfl_xor(m, o, 64));
            const float p = __expf(lgf - m);
            float s = p;
            #pragma unroll
            for (int o = 32; o; o >>= 1) s += __shfl_xor(s, o, 64);
            const float inv_s = 1.0f / s;

            double v = lg;
            double bw[8]; int ik[8];
            #pragma unroll
            for (int k = 0; k < 8; ++k) {
                double bv = v; int bi = tid;
                #pragma unroll
                for (int o = 32; o; o >>= 1) {
                    const double ov = __shfl_xor(bv, o, 64);
                    const int    oi = __shfl_xor(bi, o, 64);
                    if (ov > bv || (ov == bv && oi < bi)) { bv = ov; bi = oi; }
                }
                bw[k] = bv; ik[k] = bi;
                if (tid == bi) v = -1.0e300;
            }
            float wk[8]; float denom = 1e-20f;
            #pragma unroll
            for (int k = 0; k < 8; ++k) {
                wk[k] = __expf((float)bw[k] - m) * inv_s; denom += wk[k];
            }
            const float invd = 1.0f / denom;
            const size_t base = (size_t)tok * 8;
            const int oldtop = (int)outIdx[base];
            if (tid < 8) {
                outIdx[base + tid] = (float)ik[tid];
                outW[base + tid]   = wk[tid] * invd;
            }
            if (tid == 0 && ik[0] != oldtop) {
                atomicAdd(&wsf[NEXP + oldtop], -1.0f);
                atomicAdd(&wsf[NEXP + ik[0]],  1.0f);
            }
        }
        __syncthreads();
    }
}

__global__ void moe_final(const float* __restrict__ wsf, float* __restrict__ out) {
    const int e = threadIdx.x;  // 64 threads
    float v = wsf[e] * wsf[NEXP + e];
    #pragma unroll
    for (int o = 32; o; o >>= 1) v += __shfl_xor(v, o, 64);
    if (e == 0)
        out[2 * TOKS * 8] = v * (64.0f / ((float)TOKS * (float)TOKS));
}

// ===== fallback monolith (proven R2 path) for small ws =====
__global__ void moe_init(float* __restrict__ wsf, int n) {
    const int i = blockIdx.x * blockDim.x + threadIdx.x;
    if (i < n) wsf[i] = 0.0f;
}

__global__ void moe_w_cvt(const float* __restrict__ W, double* __restrict__ Wd) {
    const int i = blockIdx.x * blockDim.x + threadIdx.x;
    if (i < NEXP * HID) Wd[i] = (double)W[i];
}

__global__ __launch_bounds__(512, 2)
void moe_mono(const float* __restrict__ X, const double* __restrict__ Wd,
              float* __restrict__ out, float* __restrict__ wsf) {
    __shared__ double xs[64][66];
    __shared__ double L2[64][65];
    const int tid  = threadIdx.x;
    const int lane = tid & 63;
    const int wid  = __builtin_amdgcn_readfirstlane(tid >> 6);
    const int tok0 = blockIdx.x * 64;
    double acc[8] = {0., 0., 0., 0., 0., 0., 0., 0.};
    for (int h0 = 0; h0 < HID; h0 += 64) {
        #pragma unroll
        for (int i = 0; i < 8; ++i) {
            const int li = tid + i * 512;
            xs[li >> 6][li & 63] = (double)X[((size_t)(tok0 + (li >> 6)) << 12) + (h0 + (li & 63))];
        }
        __syncthreads();
        const double* wchunk = Wd + (((size_t)(wid << 3)) << 12) + h0;
        #pragma unroll 2
        for (int hh = 0; hh < 64; hh += 2) {
            const double2 xv = *(const double2*)&xs[lane][hh];
            #pragma unroll
            for (int e = 0; e < 8; ++e) {
                const double* wr = wchunk + (((size_t)e) << 12) + hh;
                acc[e] = fma(xv.x, wr[0], acc[e]);
                acc[e] = fma(xv.y, wr[1], acc[e]);
            }
        }
        __syncthreads();
    }
    #pragma unroll
    for (int e = 0; e < 8; ++e) L2[lane][(wid << 3) + e] = acc[e];
    __syncthreads();
    float* outIdx = out;
    float* outW   = out + (TOKS * 8);
    float rp = 0.0f;
    for (int tt = 0; tt < 8; ++tt) {
        const int t = (wid << 3) + tt;
        const double lg = L2[t][lane];
        const float lgf = (float)lg;
        float m = lgf;
        #pragma unroll
        for (int o = 32; o; o >>= 1) m = fmaxf(m, __shfl_xor(m, o, 64));
        const float p = __expf(lgf - m);
        float s = p;
        #pragma unroll
        for (int o = 32; o; o >>= 1) s += __shfl_xor(s, o, 64);
        const float inv_s = 1.0f / s;
        rp += p * inv_s;
        double v = lg;
        float wk[8]; int ik[8];
        #pragma unroll
        for (int k = 0; k < 8; ++k) {
            double bv = v; int bi = lane;
            #pragma unroll
            for (int o = 32; o; o >>= 1) {
                const double ov = __shfl_xor(bv, o, 64);
                const int    oi = __shfl_xor(bi, o, 64);
                if (ov > bv || (ov == bv && oi < bi)) { bv = ov; bi = oi; }
            }
            wk[k] = __expf((float)bv - m) * inv_s; ik[k] = bi;
            if (lane == bi) v = -1.0e300;
        }
        if (lane == 0) {
            const float denom = (((wk[0]+wk[1])+(wk[2]+wk[3])) +
                                 ((wk[4]+wk[5])+(wk[6]+wk[7]))) + 1e-20f;
            const float invd = 1.0f / denom;
            const size_t base = ((size_t)(tok0 + t)) << 3;
            #pragma unroll
            for (int k = 0; k < 8; ++k) {
                outIdx[base + k] = (float)ik[k];
                outW[base + k]   = wk[k] * invd;
            }
            atomicAdd(&wsf[NEXP + ik[0]], 1.0f);
        }
    }
    atomicAdd(&wsf[lane], rp);
}

extern "C" void kernel_launch(void* const* d_in, const int* in_sizes, int n_in,
                              void* d_out, int out_size, void* d_ws, size_t ws_size,
                              hipStream_t stream) {
    const float* X = (const float*)d_in[0];   // [4,4096,4096] fp32
    const float* W = (const float*)d_in[1];   // [64,4096] fp32
    float* out = (float*)d_out;
    float* wsf = (float*)d_ws;

    const size_t need = 4ull * (WS_SINK + 4096);  // sink region at 256 MB

    if (ws_size >= need) {
        unsigned short* Bpk = (unsigned short*)(wsf + WS_BPACK);
        moe_prep<<<(NEXP * HID + 255) / 256, 256, 0, stream>>>(W, Bpk, wsf);
        moe_fused<<<TOKS / 64, 512, 0, stream>>>(X, Bpk, out, wsf);
        moe_fix<<<256, 256, 0, stream>>>(X, W, out, wsf);
        moe_final<<<1, 64, 0, stream>>>(wsf, out);
        // diagnostic probe LAST: memory skeleton only, x8 amplification
        moe_probe_stage<<<TOKS / 64, 512, 0, stream>>>(X, Bpk, wsf + WS_SINK);
    } else {
        double* Wd = (double*)d_ws;
        float* wsf2 = (float*)(Wd + NEXP * HID);
        moe_w_cvt<<<(NEXP * HID + 255) / 256, 256, 0, stream>>>(W, Wd);
        moe_init<<<1, 256, 0, stream>>>(wsf2, 128);
        moe_mono<<<TOKS / 64, 512, 0, stream>>>(X, Wd, out, wsf2);
        moe_final<<<1, 64, 0, stream>>>(wsf2, out);
    }
}

// Round 18
// 293.958 us; speedup vs baseline: 1.8283x; 1.8283x over previous
//
#include <hip/hip_runtime.h>
#include <hip/hip_bf16.h>

#define TOKS 16384
#define HID  4096
#define NEXP 64
#define EPS  1e-4f   // flag threshold; trunc-split logit err ~6e-6 -> 16x margin

// ===== ws layout (floats) =====
// [0..63] prob sums | [64..127] argmax counts | int@[128] flag count |
// ints [192..192+16384) flag list | [16576) Bpack (1 MB, bf16 hi/lo plane-split frag-pack)
#define WS_FLAGCNT  128
#define WS_FLAGLIST 192
#define WS_BPACK    16576

typedef __attribute__((ext_vector_type(8))) short short8_t;
typedef __attribute__((ext_vector_type(4))) float f32x4;

static __device__ __forceinline__ unsigned short f2bf_rn(float x) {
    unsigned u = __builtin_bit_cast(unsigned, x);
    u = (u + 0x7fffu + ((u >> 16) & 1u)) >> 16;
    return (unsigned short)u;
}
static __device__ __forceinline__ float bf2f(unsigned short h) {
    return __builtin_bit_cast(float, (unsigned)h << 16);
}
static __device__ __forceinline__ void gl2lds16(const void* g, void* l) {
    __builtin_amdgcn_global_load_lds(
        (const __attribute__((address_space(1))) unsigned int*)g,
        (__attribute__((address_space(3))) unsigned int*)l, 16, 0, 0);
}

// ---------- prep: W -> frag-packed bf16, hi/lo planes per (kt,nt): 2 KB contiguous ----------
// u16 index: (kt*4+nt)*1024 + plane*512 + lane*8 + j ; lane=(n&15)|(((k>>3)&3)<<4), j=k&7
__global__ void moe_prep(const float* __restrict__ W, unsigned short* __restrict__ Bpk,
                         float* __restrict__ wsf) {
    const int idx = blockIdx.x * blockDim.x + threadIdx.x;
    if (idx < 192) wsf[idx] = 0.0f;
    if (idx >= NEXP * HID) return;
    const int n = idx >> 12;
    const int k = idx & 4095;
    const float w = W[idx];
    const unsigned short hi = f2bf_rn(w);
    const unsigned short lo = f2bf_rn(w - bf2f(hi));
    const int kt   = k >> 5;
    const int nt   = n >> 4;
    const int lane = (n & 15) | (((k >> 3) & 3) << 4);
    const int j    = k & 7;
    const int dst  = (((kt << 2) + nt) << 10) + (lane << 3) + j;
    Bpk[dst]       = hi;
    Bpk[dst + 512] = lo;
}

// ---------- fused: BARRIER-FREE wave-private pipelined MFMA GEMM + epilogue ----------
// 1024 blocks x 512 thr. Block: 16 tokens. Wave w = (kc=w&1, nt=w>>1):
// K-half (2048 = 32 steps of 64) x 16 experts. Each wave owns an 18 KB private
// LDS region (X dbuf 2x5120 + B dbuf 2x4096) and pipelines with its OWN
// counted vmcnt(9) -- ZERO s_barrier in the GEMM loop. Wave chains overlap freely.
__global__ __launch_bounds__(512, 1)
void moe_fused(const float* __restrict__ X, const unsigned short* __restrict__ Bpk,
               float* __restrict__ out, float* __restrict__ wsf) {
    __shared__ __align__(16) char lds[8][18432];          // 144 KB
    float (*L)[68] = (float (*)[68])&lds[0][0];           // epilogue alias (4352 B)

    const int tid  = threadIdx.x;
    const int lane = tid & 63;
    const int w    = tid >> 6;                 // 0..7
    const int kc   = w & 1;                    // K half
    const int nt   = w >> 1;                   // expert tile 0..3
    const int g    = lane >> 4;                // 0..3
    const int tok0 = blockIdx.x * 16;
    char* wb = &lds[w][0];                     // wave-private region

    f32x4 acc = (f32x4){0.f, 0.f, 0.f, 0.f};

    // X slot map: 5 x 1KB lane-monotonic slots over 16 rows x 272 B (R15-proven map)
    int xlds[5]; size_t xsrc[5];
    #pragma unroll
    for (int i = 0; i < 5; ++i) {
        const int byte = i * 1024 + (lane << 4);
        int row = byte / 272;
        const int inrow = byte - row * 272;
        int col = (inrow < 256) ? (inrow >> 2) : 0;      // pad lanes dup col 0
        if (row > 15) { row = 15; col = 0; }             // slot-4 tail dup
        xlds[i] = i * 1024;
        xsrc[i] = (size_t)(tok0 + row) * HID + col;
    }

    // stage global step gs into private buffer bf: 5 X + 4 B instrs (9 vmcnt events)
    #define STAGE(bf, gs)                                                              \
    {                                                                                  \
        const int k0_ = (gs) << 6;                                                     \
        _Pragma("unroll")                                                              \
        for (int i = 0; i < 5; ++i)                                                    \
            gl2lds16(X + xsrc[i] + k0_, (void*)(wb + (bf) * 5120 + xlds[i]));          \
        _Pragma("unroll")                                                              \
        for (int j = 0; j < 4; ++j) {                                                  \
            const int kt_ = ((gs) << 1) + (j >> 1);                                    \
            gl2lds16((const char*)Bpk + (((size_t)((kt_ << 2) + nt)) << 11)            \
                         + ((j & 1) << 10) + (lane << 4),                              \
                     (void*)(wb + 10240 + (bf) * 4096 + (j >> 1) * 2048 + ((j & 1) << 10))); \
        }                                                                              \
    }

    // one compute step from private buffer bf (8 ds_read_b128 + cvt + 6 MFMA)
    #define COMPUTE(bf)                                                                \
    {                                                                                  \
        const char* ab = wb + (bf) * 5120 + (lane & 15) * 272;                         \
        const char* bb = wb + 10240 + (bf) * 4096;                                     \
        _Pragma("unroll")                                                              \
        for (int ktl = 0; ktl < 2; ++ktl) {                                            \
            const float4 a0 = *(const float4*)(ab + ktl * 128 + g * 32);               \
            const float4 a1 = *(const float4*)(ab + ktl * 128 + g * 32 + 16);          \
            const float xv[8] = {a0.x, a0.y, a0.z, a0.w, a1.x, a1.y, a1.z, a1.w};      \
            short8_t ah, al;                                                           \
            _Pragma("unroll")                                                          \
            for (int j = 0; j < 8; ++j) {                                              \
                const unsigned u = __builtin_bit_cast(unsigned, xv[j]);                \
                ah[j] = (short)(u >> 16);                                              \
                const float hif = __builtin_bit_cast(float, u & 0xFFFF0000u);          \
                al[j] = (short)(__builtin_bit_cast(unsigned, xv[j] - hif) >> 16);      \
            }                                                                          \
            const short8_t bh = *(const short8_t*)(bb + ktl * 2048 + (lane << 4));     \
            const short8_t bl = *(const short8_t*)(bb + ktl * 2048 + 1024 + (lane << 4)); \
            acc = __builtin_amdgcn_mfma_f32_16x16x32_bf16(ah, bh, acc, 0, 0, 0);       \
            acc = __builtin_amdgcn_mfma_f32_16x16x32_bf16(al, bh, acc, 0, 0, 0);       \
            acc = __builtin_amdgcn_mfma_f32_16x16x32_bf16(ah, bl, acc, 0, 0, 0);       \
        }                                                                              \
    }

    const int gsbase = kc << 5;                // 32 steps per K-half
    STAGE(0, gsbase);
    for (int s = 0; s < 31; ++s) {
        STAGE((s + 1) & 1, gsbase + s + 1);    // issue next stage FIRST
        asm volatile("s_waitcnt vmcnt(9)" ::: "memory");   // wait stage(s) only
        __builtin_amdgcn_sched_barrier(0);
        COMPUTE(s & 1);
    }
    asm volatile("s_waitcnt vmcnt(0)" ::: "memory");       // drain stage(31)
    __builtin_amdgcn_sched_barrier(0);
    COMPUTE(1);

    // ---- cross-kc reduce into L (first barriers of the kernel) ----
    __syncthreads();
    if (kc == 0) {
        #pragma unroll
        for (int r = 0; r < 4; ++r)
            L[(g << 2) + r][(nt << 4) + (lane & 15)] = acc[r];
    }
    __syncthreads();
    if (kc == 1) {
        #pragma unroll
        for (int r = 0; r < 4; ++r)
            L[(g << 2) + r][(nt << 4) + (lane & 15)] += acc[r];
    }
    __syncthreads();

    // ---- epilogue: wave w handles tokens w*2, w*2+1; lane = expert ----
    float* outIdx = out;
    float* outW   = out + TOKS * 8;
    int* flagcnt  = (int*)wsf + WS_FLAGCNT;
    int* flaglist = (int*)wsf + WS_FLAGLIST;

    float rp = 0.f;
    #pragma unroll
    for (int tt = 0; tt < 2; ++tt) {
        const int tl = (w << 1) + tt;
        const float lg = L[tl][lane];

        // bitonic sort-64, descending by (value, then lower index first)
        float v = lg; int idx = lane;
        #pragma unroll
        for (int size = 2; size <= 64; size <<= 1) {
            #pragma unroll
            for (int str = size >> 1; str > 0; str >>= 1) {
                const float ov = __shfl_xor(v, str, 64);
                const int   oi = __shfl_xor(idx, str, 64);
                const bool pb = (ov > v) || (ov == v && oi < idx);
                const bool keepFirst = ((lane & str) == 0) == ((lane & size) == 0);
                if (pb == keepFirst) { v = ov; idx = oi; }
            }
        }

        const float m = __shfl(v, 0, 64);
        const float p = __expf(lg - m);
        float sdenom = p;
        #pragma unroll
        for (int o = 32; o; o >>= 1) sdenom += __shfl_xor(sdenom, o, 64);
        const float inv_s = 1.0f / sdenom;
        rp += p * inv_s;

        const float wkv = __expf(v - m) * inv_s;
        float d8 = (lane < 8) ? wkv : 0.f;
        #pragma unroll
        for (int o = 1; o < 8; o <<= 1) d8 += __shfl_xor(d8, o, 64);
        const float invd = 1.0f / (d8 + 1e-20f);
        const float nv = __shfl_down(v, 1, 64);
        const bool flg = __any(lane < 8 && (v - nv) < EPS);

        const int gtok = tok0 + tl;
        if (lane < 8) {
            outIdx[(size_t)gtok * 8 + lane] = (float)idx;
            outW[(size_t)gtok * 8 + lane]   = wkv * invd;
        }
        if (lane == 0) {
            atomicAdd(&wsf[NEXP + idx], 1.0f);
            if (flg) {
                const int pos = atomicAdd(flagcnt, 1);
                if (pos < TOKS) flaglist[pos] = gtok;
            }
        }
    }
    atomicAdd(&wsf[lane], rp);
    #undef STAGE
    #undef COMPUTE
}

// ---------- exact fp64 redo for flagged tokens ----------
__global__ __launch_bounds__(256, 2)
void moe_fix(const float* __restrict__ X, const float* __restrict__ W,
             float* __restrict__ out, float* __restrict__ wsf) {
    __shared__ double red[256];
    const int tid = threadIdx.x;
    const int e   = tid & 63;
    const int kc  = tid >> 6;
    const int nf  = min(*((int*)wsf + WS_FLAGCNT), TOKS);
    const int* flaglist = (const int*)wsf + WS_FLAGLIST;
    float* outIdx = out;
    float* outW   = out + TOKS * 8;

    for (int fi = blockIdx.x; fi < nf; fi += gridDim.x) {
        const int tok = flaglist[fi];
        const float* xrow = X + (size_t)tok * HID + kc * 1024;
        const float* wrow = W + (size_t)e  * HID + kc * 1024;
        double part = 0.0;
        for (int j = 0; j < 1024; j += 4) {
            const float4 xv = *(const float4*)(xrow + j);
            const float4 wv = *(const float4*)(wrow + j);
            part = fma((double)xv.x, (double)wv.x, part);
            part = fma((double)xv.y, (double)wv.y, part);
            part = fma((double)xv.z, (double)wv.z, part);
            part = fma((double)xv.w, (double)wv.w, part);
        }
        red[tid] = part;
        __syncthreads();
        if (tid < 64) {
            const double lg = ((red[tid] + red[64 + tid]) + red[128 + tid]) + red[192 + tid];
            const float lgf = (float)lg;
            float m = lgf;
            #pragma unroll
            for (int o = 32; o; o >>= 1) m = fmaxf(m, __shfl_xor(m, o, 64));
            const float p = __expf(lgf - m);
            float s = p;
            #pragma unroll
            for (int o = 32; o; o >>= 1) s += __shfl_xor(s, o, 64);
            const float inv_s = 1.0f / s;

            double v = lg;
            double bw[8]; int ik[8];
            #pragma unroll
            for (int k = 0; k < 8; ++k) {
                double bv = v; int bi = tid;
                #pragma unroll
                for (int o = 32; o; o >>= 1) {
                    const double ov = __shfl_xor(bv, o, 64);
                    const int    oi = __shfl_xor(bi, o, 64);
                    if (ov > bv || (ov == bv && oi < bi)) { bv = ov; bi = oi; }
                }
                bw[k] = bv; ik[k] = bi;
                if (tid == bi) v = -1.0e300;
            }
            float wk[8]; float denom = 1e-20f;
            #pragma unroll
            for (int k = 0; k < 8; ++k) {
                wk[k] = __expf((float)bw[k] - m) * inv_s; denom += wk[k];
            }
            const float invd = 1.0f / denom;
            const size_t base = (size_t)tok * 8;
            const int oldtop = (int)outIdx[base];
            if (tid < 8) {
                outIdx[base + tid] = (float)ik[tid];
                outW[base + tid]   = wk[tid] * invd;
            }
            if (tid == 0 && ik[0] != oldtop) {
                atomicAdd(&wsf[NEXP + oldtop], -1.0f);
                atomicAdd(&wsf[NEXP + ik[0]],  1.0f);
            }
        }
        __syncthreads();
    }
}

__global__ void moe_final(const float* __restrict__ wsf, float* __restrict__ out) {
    const int e = threadIdx.x;  // 64 threads
    float v = wsf[e] * wsf[NEXP + e];
    #pragma unroll
    for (int o = 32; o; o >>= 1) v += __shfl_xor(v, o, 64);
    if (e == 0)
        out[2 * TOKS * 8] = v * (64.0f / ((float)TOKS * (float)TOKS));
}

// ===== fallback monolith (proven R2 path) for small ws =====
__global__ void moe_init(float* __restrict__ wsf, int n) {
    const int i = blockIdx.x * blockDim.x + threadIdx.x;
    if (i < n) wsf[i] = 0.0f;
}

__global__ void moe_w_cvt(const float* __restrict__ W, double* __restrict__ Wd) {
    const int i = blockIdx.x * blockDim.x + threadIdx.x;
    if (i < NEXP * HID) Wd[i] = (double)W[i];
}

__global__ __launch_bounds__(512, 2)
void moe_mono(const float* __restrict__ X, const double* __restrict__ Wd,
              float* __restrict__ out, float* __restrict__ wsf) {
    __shared__ double xs[64][66];
    __shared__ double L2[64][65];
    const int tid  = threadIdx.x;
    const int lane = tid & 63;
    const int wid  = __builtin_amdgcn_readfirstlane(tid >> 6);
    const int tok0 = blockIdx.x * 64;
    double acc[8] = {0., 0., 0., 0., 0., 0., 0., 0.};
    for (int h0 = 0; h0 < HID; h0 += 64) {
        #pragma unroll
        for (int i = 0; i < 8; ++i) {
            const int li = tid + i * 512;
            xs[li >> 6][li & 63] = (double)X[((size_t)(tok0 + (li >> 6)) << 12) + (h0 + (li & 63))];
        }
        __syncthreads();
        const double* wchunk = Wd + (((size_t)(wid << 3)) << 12) + h0;
        #pragma unroll 2
        for (int hh = 0; hh < 64; hh += 2) {
            const double2 xv = *(const double2*)&xs[lane][hh];
            #pragma unroll
            for (int e = 0; e < 8; ++e) {
                const double* wr = wchunk + (((size_t)e) << 12) + hh;
                acc[e] = fma(xv.x, wr[0], acc[e]);
                acc[e] = fma(xv.y, wr[1], acc[e]);
            }
        }
        __syncthreads();
    }
    #pragma unroll
    for (int e = 0; e < 8; ++e) L2[lane][(wid << 3) + e] = acc[e];
    __syncthreads();
    float* outIdx = out;
    float* outW   = out + (TOKS * 8);
    float rp = 0.0f;
    for (int tt = 0; tt < 8; ++tt) {
        const int t = (wid << 3) + tt;
        const double lg = L2[t][lane];
        const float lgf = (float)lg;
        float m = lgf;
        #pragma unroll
        for (int o = 32; o; o >>= 1) m = fmaxf(m, __shfl_xor(m, o, 64));
        const float p = __expf(lgf - m);
        float s = p;
        #pragma unroll
        for (int o = 32; o; o >>= 1) s += __shfl_xor(s, o, 64);
        const float inv_s = 1.0f / s;
        rp += p * inv_s;
        double v = lg;
        float wk[8]; int ik[8];
        #pragma unroll
        for (int k = 0; k < 8; ++k) {
            double bv = v; int bi = lane;
            #pragma unroll
            for (int o = 32; o; o >>= 1) {
                const double ov = __shfl_xor(bv, o, 64);
                const int    oi = __shfl_xor(bi, o, 64);
                if (ov > bv || (ov == bv && oi < bi)) { bv = ov; bi = oi; }
            }
            wk[k] = __expf((float)bv - m) * inv_s; ik[k] = bi;
            if (lane == bi) v = -1.0e300;
        }
        if (lane == 0) {
            const float denom = (((wk[0]+wk[1])+(wk[2]+wk[3])) +
                                 ((wk[4]+wk[5])+(wk[6]+wk[7]))) + 1e-20f;
            const float invd = 1.0f / denom;
            const size_t base = ((size_t)(tok0 + t)) << 3;
            #pragma unroll
            for (int k = 0; k < 8; ++k) {
                outIdx[base + k] = (float)ik[k];
                outW[base + k]   = wk[k] * invd;
            }
            atomicAdd(&wsf[NEXP + ik[0]], 1.0f);
        }
    }
    atomicAdd(&wsf[lane], rp);
}

extern "C" void kernel_launch(void* const* d_in, const int* in_sizes, int n_in,
                              void* d_out, int out_size, void* d_ws, size_t ws_size,
                              hipStream_t stream) {
    const float* X = (const float*)d_in[0];   // [4,4096,4096] fp32
    const float* W = (const float*)d_in[1];   // [64,4096] fp32
    float* out = (float*)d_out;
    float* wsf = (float*)d_ws;

    const size_t need = 4ull * WS_BPACK + 2ull * 524288;  // slots + Bpack ~ 1.1 MB

    if (ws_size >= need) {
        unsigned short* Bpk = (unsigned short*)(wsf + WS_BPACK);
        moe_prep<<<(NEXP * HID + 255) / 256, 256, 0, stream>>>(W, Bpk, wsf);
        moe_fused<<<TOKS / 16, 512, 0, stream>>>(X, Bpk, out, wsf);
        moe_fix<<<256, 256, 0, stream>>>(X, W, out, wsf);
        moe_final<<<1, 64, 0, stream>>>(wsf, out);
    } else {
        double* Wd = (double*)d_ws;
        float* wsf2 = (float*)(Wd + NEXP * HID);
        moe_w_cvt<<<(NEXP * HID + 255) / 256, 256, 0, stream>>>(W, Wd);
        moe_init<<<1, 256, 0, stream>>>(wsf2, 128);
        moe_mono<<<TOKS / 64, 512, 0, stream>>>(X, Wd, out, wsf2);
        moe_final<<<1, 64, 0, stream>>>(wsf2, out);
    }
}

// Round 19
// 242.582 us; speedup vs baseline: 2.2155x; 1.2118x over previous
//
#include <hip/hip_runtime.h>
#include <hip/hip_bf16.h>

#define TOKS 16384
#define HID  4096
#define NEXP 64
#define EPS  1e-4f   // flag threshold; trunc-split logit err ~6e-6 -> 16x margin

// ===== ws layout (floats) =====
// [0..63] prob sums | [64..127] argmax counts | int@[128] flag count |
// ints [192..192+16384) flag list | [16576) Bpack (1 MB, bf16 hi/lo per (kt,nt))
#define WS_FLAGCNT  128
#define WS_FLAGLIST 192
#define WS_BPACK    16576

typedef __attribute__((ext_vector_type(8))) short short8_t;
typedef __attribute__((ext_vector_type(4))) float f32x4;

static __device__ __forceinline__ unsigned short f2bf_rn(float x) {
    unsigned u = __builtin_bit_cast(unsigned, x);
    u = (u + 0x7fffu + ((u >> 16) & 1u)) >> 16;
    return (unsigned short)u;
}
static __device__ __forceinline__ float bf2f(unsigned short h) {
    return __builtin_bit_cast(float, (unsigned)h << 16);
}
static __device__ __forceinline__ void gl2lds16(const void* g, void* l) {
    __builtin_amdgcn_global_load_lds(
        (const __attribute__((address_space(1))) unsigned int*)g,
        (__attribute__((address_space(3))) unsigned int*)l, 16, 0, 0);
}

// ---------- prep: W -> frag-packed bf16; (kt,nt) block = 2 KB: hi 1 KB | lo 1 KB ----------
// u16 index: (kt*4+nt)*1024 + plane*512 + lane*8 + j ; lane=(n&15)|(((k>>3)&3)<<4), j=k&7
__global__ void moe_prep(const float* __restrict__ W, unsigned short* __restrict__ Bpk,
                         float* __restrict__ wsf) {
    const int idx = blockIdx.x * blockDim.x + threadIdx.x;
    if (idx < 192) wsf[idx] = 0.0f;
    if (idx >= NEXP * HID) return;
    const int n = idx >> 12;
    const int k = idx & 4095;
    const float w = W[idx];
    const unsigned short hi = f2bf_rn(w);
    const unsigned short lo = f2bf_rn(w - bf2f(hi));
    const int kt   = k >> 5;
    const int nt   = n >> 4;
    const int lane = (n & 15) | (((k >> 3) & 3) << 4);
    const int j    = k & 7;
    const int dst  = (((kt << 2) + nt) << 10) + (lane << 3) + j;
    Bpk[dst]       = hi;
    Bpk[dst + 512] = lo;
}

// ---------- fused: DEEP-pipelined MFMA GEMM (depth 6) + softmax + bitonic top-8 ----------
// 256 blocks x 512 thr (8 waves), 1 block/CU (LDS 128 KB). Block: 64 tok x 64 exp,
// 128 K-steps of BK=32. 8-deep LDS buffers, prefetch distance 6 -> 96 KB in flight
// per CU (vs 12 KB before) => BW-bound, not latency-bound. vmcnt(12) waits only
// stage(s); 6 stages stay in flight across the one s_barrier per step.
__global__ __launch_bounds__(512, 1)
void moe_fused(const float* __restrict__ X, const unsigned short* __restrict__ Bpk,
               float* __restrict__ out, float* __restrict__ wsf) {
    __shared__ __align__(16) char xbuf[8][8192];   // X: 64 rows x 128 B (chunk-XOR swz)
    __shared__ __align__(16) char bbuf[8][8192];   // B: 4 ntiles x (hi|lo) per step
    float (*L)[68] = (float (*)[68])&xbuf[0][0];   // epilogue alias (17408 B)

    const int tid  = threadIdx.x;
    const int lane = tid & 63;
    const int w    = tid >> 6;                 // 0..7
    const int mt   = w & 3;                    // m-tile (16 tokens)
    const int nh   = w >> 2;                   // n-half (2 ntiles)
    const int g    = lane >> 4;                // 0..3
    const int r    = lane & 15;                // token row within tile
    const int tok0 = blockIdx.x * 64;

    f32x4 acc[2];
    acc[0] = (f32x4){0.f, 0.f, 0.f, 0.f};
    acc[1] = (f32x4){0.f, 0.f, 0.f, 0.f};

    // X staging: wave w covers rows w*8..w*8+7 (128 B each); lane L -> row w*8+L/8,
    // LDS position p=L%8 holds global chunk p^(row&7)  [source-XOR swizzle, R12-proven]
    const int xrow = (w << 3) + (lane >> 3);
    const int xchk = (lane & 7) ^ ((lane >> 3) & 7);
    const size_t xsrc = (size_t)(tok0 + xrow) * HID + (xchk << 2);
    const char* BpkB = (const char*)Bpk;

    // stage step ss into buffer bf: 1 X + 1 B gl_lds per wave (2 vmcnt events)
    #define STAGE(bf, ss)                                                              \
    {                                                                                  \
        gl2lds16(X + xsrc + ((ss) << 5), (void*)(&xbuf[bf][0] + (w << 10)));           \
        gl2lds16(BpkB + ((size_t)(ss) << 13) + (w << 10) + (lane << 4),                \
                 (void*)(&bbuf[bf][0] + (w << 10)));                                   \
    }

    #pragma unroll
    for (int i = 0; i < 6; ++i) STAGE(i, i);   // prologue: fill 6 stages

    for (int s = 0; s < 128; ++s) {
        const int cur = s & 7;
        const int ss = (s + 6 < 128) ? (s + 6) : 127;   // tail dups safe (bufs dead)
        STAGE((s + 6) & 7, ss);
        asm volatile("s_waitcnt vmcnt(12)" ::: "memory");  // drain stage(s) only
        __builtin_amdgcn_s_barrier();
        __builtin_amdgcn_sched_barrier(0);

        const char* ab = &xbuf[cur][0] + (((mt << 4) + r) << 7);
        const char* bb = &bbuf[cur][0];
        // A: global chunks 2g, 2g+1 of this row, stored at position c^(r&7)
        const float4 a0 = *(const float4*)(ab + ((((g << 1))     ^ (r & 7)) << 4));
        const float4 a1 = *(const float4*)(ab + ((((g << 1) | 1) ^ (r & 7)) << 4));
        const float xv[8] = {a0.x, a0.y, a0.z, a0.w, a1.x, a1.y, a1.z, a1.w};
        short8_t ah, al;
        #pragma unroll
        for (int j = 0; j < 8; ++j) {          // exact truncation split: x = hif + lof
            const unsigned u = __builtin_bit_cast(unsigned, xv[j]);
            ah[j] = (short)(u >> 16);
            const float hif = __builtin_bit_cast(float, u & 0xFFFF0000u);
            al[j] = (short)(__builtin_bit_cast(unsigned, xv[j] - hif) >> 16);
        }
        #pragma unroll
        for (int ntl = 0; ntl < 2; ++ntl) {
            const char* bp = bb + (((nh << 1) + ntl) << 11) + (lane << 4);
            const short8_t bh = *(const short8_t*)bp;
            const short8_t bl = *(const short8_t*)(bp + 1024);
            acc[ntl] = __builtin_amdgcn_mfma_f32_16x16x32_bf16(ah, bh, acc[ntl], 0, 0, 0);
            acc[ntl] = __builtin_amdgcn_mfma_f32_16x16x32_bf16(al, bh, acc[ntl], 0, 0, 0);
            acc[ntl] = __builtin_amdgcn_mfma_f32_16x16x32_bf16(ah, bl, acc[ntl], 0, 0, 0);
        }
    }
    asm volatile("s_waitcnt vmcnt(0)" ::: "memory");
    __syncthreads();

    // ---- logits -> L[token][expert] (aliases dead staging bufs) ----
    #pragma unroll
    for (int ntl = 0; ntl < 2; ++ntl)
        #pragma unroll
        for (int rr = 0; rr < 4; ++rr)
            L[(mt << 4) + (g << 2) + rr][(nh << 5) + (ntl << 4) + r] = acc[ntl][rr];
    __syncthreads();

    // ---- epilogue: wave w handles tokens w*8 .. w*8+7; lane = expert ----
    float* outIdx = out;
    float* outW   = out + TOKS * 8;
    int* flagcnt  = (int*)wsf + WS_FLAGCNT;
    int* flaglist = (int*)wsf + WS_FLAGLIST;

    float rp = 0.f;
    #pragma unroll
    for (int tt = 0; tt < 8; ++tt) {
        const int tl = (w << 3) + tt;
        const float lg = L[tl][lane];

        // bitonic sort-64, descending by (value, then lower index first)
        float v = lg; int idx = lane;
        #pragma unroll
        for (int size = 2; size <= 64; size <<= 1) {
            #pragma unroll
            for (int str = size >> 1; str > 0; str >>= 1) {
                const float ov = __shfl_xor(v, str, 64);
                const int   oi = __shfl_xor(idx, str, 64);
                const bool pb = (ov > v) || (ov == v && oi < idx);
                const bool keepFirst = ((lane & str) == 0) == ((lane & size) == 0);
                if (pb == keepFirst) { v = ov; idx = oi; }
            }
        }

        const float m = __shfl(v, 0, 64);
        const float p = __expf(lg - m);
        float sdenom = p;
        #pragma unroll
        for (int o = 32; o; o >>= 1) sdenom += __shfl_xor(sdenom, o, 64);
        const float inv_s = 1.0f / sdenom;
        rp += p * inv_s;

        const float wkv = __expf(v - m) * inv_s;
        float d8 = (lane < 8) ? wkv : 0.f;
        #pragma unroll
        for (int o = 1; o < 8; o <<= 1) d8 += __shfl_xor(d8, o, 64);
        const float invd = 1.0f / (d8 + 1e-20f);
        const float nv = __shfl_down(v, 1, 64);
        const bool flg = __any(lane < 8 && (v - nv) < EPS);

        const int gtok = tok0 + tl;
        if (lane < 8) {
            outIdx[(size_t)gtok * 8 + lane] = (float)idx;
            outW[(size_t)gtok * 8 + lane]   = wkv * invd;
        }
        if (lane == 0) {
            atomicAdd(&wsf[NEXP + idx], 1.0f);
            if (flg) {
                const int pos = atomicAdd(flagcnt, 1);
                if (pos < TOKS) flaglist[pos] = gtok;
            }
        }
    }
    atomicAdd(&wsf[lane], rp);
    #undef STAGE
}

// ---------- exact fp64 redo for flagged tokens ----------
__global__ __launch_bounds__(256, 2)
void moe_fix(const float* __restrict__ X, const float* __restrict__ W,
             float* __restrict__ out, float* __restrict__ wsf) {
    __shared__ double red[256];
    const int tid = threadIdx.x;
    const int e   = tid & 63;
    const int kc  = tid >> 6;
    const int nf  = min(*((int*)wsf + WS_FLAGCNT), TOKS);
    const int* flaglist = (const int*)wsf + WS_FLAGLIST;
    float* outIdx = out;
    float* outW   = out + TOKS * 8;

    for (int fi = blockIdx.x; fi < nf; fi += gridDim.x) {
        const int tok = flaglist[fi];
        const float* xrow = X + (size_t)tok * HID + kc * 1024;
        const float* wrow = W + (size_t)e  * HID + kc * 1024;
        double part = 0.0;
        for (int j = 0; j < 1024; j += 4) {
            const float4 xv = *(const float4*)(xrow + j);
            const float4 wv = *(const float4*)(wrow + j);
            part = fma((double)xv.x, (double)wv.x, part);
            part = fma((double)xv.y, (double)wv.y, part);
            part = fma((double)xv.z, (double)wv.z, part);
            part = fma((double)xv.w, (double)wv.w, part);
        }
        red[tid] = part;
        __syncthreads();
        if (tid < 64) {
            const double lg = ((red[tid] + red[64 + tid]) + red[128 + tid]) + red[192 + tid];
            const float lgf = (float)lg;
            float m = lgf;
            #pragma unroll
            for (int o = 32; o; o >>= 1) m = fmaxf(m, __shfl_xor(m, o, 64));
            const float p = __expf(lgf - m);
            float s = p;
            #pragma unroll
            for (int o = 32; o; o >>= 1) s += __shfl_xor(s, o, 64);
            const float inv_s = 1.0f / s;

            double v = lg;
            double bw[8]; int ik[8];
            #pragma unroll
            for (int k = 0; k < 8; ++k) {
                double bv = v; int bi = tid;
                #pragma unroll
                for (int o = 32; o; o >>= 1) {
                    const double ov = __shfl_xor(bv, o, 64);
                    const int    oi = __shfl_xor(bi, o, 64);
                    if (ov > bv || (ov == bv && oi < bi)) { bv = ov; bi = oi; }
                }
                bw[k] = bv; ik[k] = bi;
                if (tid == bi) v = -1.0e300;
            }
            float wk[8]; float denom = 1e-20f;
            #pragma unroll
            for (int k = 0; k < 8; ++k) {
                wk[k] = __expf((float)bw[k] - m) * inv_s; denom += wk[k];
            }
            const float invd = 1.0f / denom;
            const size_t base = (size_t)tok * 8;
            const int oldtop = (int)outIdx[base];
            if (tid < 8) {
                outIdx[base + tid] = (float)ik[tid];
                outW[base + tid]   = wk[tid] * invd;
            }
            if (tid == 0 && ik[0] != oldtop) {
                atomicAdd(&wsf[NEXP + oldtop], -1.0f);
                atomicAdd(&wsf[NEXP + ik[0]],  1.0f);
            }
        }
        __syncthreads();
    }
}

__global__ void moe_final(const float* __restrict__ wsf, float* __restrict__ out) {
    const int e = threadIdx.x;  // 64 threads
    float v = wsf[e] * wsf[NEXP + e];
    #pragma unroll
    for (int o = 32; o; o >>= 1) v += __shfl_xor(v, o, 64);
    if (e == 0)
        out[2 * TOKS * 8] = v * (64.0f / ((float)TOKS * (float)TOKS));
}

// ===== fallback monolith (proven R2 path) for small ws =====
__global__ void moe_init(float* __restrict__ wsf, int n) {
    const int i = blockIdx.x * blockDim.x + threadIdx.x;
    if (i < n) wsf[i] = 0.0f;
}

__global__ void moe_w_cvt(const float* __restrict__ W, double* __restrict__ Wd) {
    const int i = blockIdx.x * blockDim.x + threadIdx.x;
    if (i < NEXP * HID) Wd[i] = (double)W[i];
}

__global__ __launch_bounds__(512, 2)
void moe_mono(const float* __restrict__ X, const double* __restrict__ Wd,
              float* __restrict__ out, float* __restrict__ wsf) {
    __shared__ double xs[64][66];
    __shared__ double L2[64][65];
    const int tid  = threadIdx.x;
    const int lane = tid & 63;
    const int wid  = __builtin_amdgcn_readfirstlane(tid >> 6);
    const int tok0 = blockIdx.x * 64;
    double acc[8] = {0., 0., 0., 0., 0., 0., 0., 0.};
    for (int h0 = 0; h0 < HID; h0 += 64) {
        #pragma unroll
        for (int i = 0; i < 8; ++i) {
            const int li = tid + i * 512;
            xs[li >> 6][li & 63] = (double)X[((size_t)(tok0 + (li >> 6)) << 12) + (h0 + (li & 63))];
        }
        __syncthreads();
        const double* wchunk = Wd + (((size_t)(wid << 3)) << 12) + h0;
        #pragma unroll 2
        for (int hh = 0; hh < 64; hh += 2) {
            const double2 xv = *(const double2*)&xs[lane][hh];
            #pragma unroll
            for (int e = 0; e < 8; ++e) {
                const double* wr = wchunk + (((size_t)e) << 12) + hh;
                acc[e] = fma(xv.x, wr[0], acc[e]);
                acc[e] = fma(xv.y, wr[1], acc[e]);
            }
        }
        __syncthreads();
    }
    #pragma unroll
    for (int e = 0; e < 8; ++e) L2[lane][(wid << 3) + e] = acc[e];
    __syncthreads();
    float* outIdx = out;
    float* outW   = out + (TOKS * 8);
    float rp = 0.0f;
    for (int tt = 0; tt < 8; ++tt) {
        const int t = (wid << 3) + tt;
        const double lg = L2[t][lane];
        const float lgf = (float)lg;
        float m = lgf;
        #pragma unroll
        for (int o = 32; o; o >>= 1) m = fmaxf(m, __shfl_xor(m, o, 64));
        const float p = __expf(lgf - m);
        float s = p;
        #pragma unroll
        for (int o = 32; o; o >>= 1) s += __shfl_xor(s, o, 64);
        const float inv_s = 1.0f / s;
        rp += p * inv_s;
        double v = lg;
        float wk[8]; int ik[8];
        #pragma unroll
        for (int k = 0; k < 8; ++k) {
            double bv = v; int bi = lane;
            #pragma unroll
            for (int o = 32; o; o >>= 1) {
                const double ov = __shfl_xor(bv, o, 64);
                const int    oi = __shfl_xor(bi, o, 64);
                if (ov > bv || (ov == bv && oi < bi)) { bv = ov; bi = oi; }
            }
            wk[k] = __expf((float)bv - m) * inv_s; ik[k] = bi;
            if (lane == bi) v = -1.0e300;
        }
        if (lane == 0) {
            const float denom = (((wk[0]+wk[1])+(wk[2]+wk[3])) +
                                 ((wk[4]+wk[5])+(wk[6]+wk[7]))) + 1e-20f;
            const float invd = 1.0f / denom;
            const size_t base = ((size_t)(tok0 + t)) << 3;
            #pragma unroll
            for (int k = 0; k < 8; ++k) {
                outIdx[base + k] = (float)ik[k];
                outW[base + k]   = wk[k] * invd;
            }
            atomicAdd(&wsf[NEXP + ik[0]], 1.0f);
        }
    }
    atomicAdd(&wsf[lane], rp);
}

extern "C" void kernel_launch(void* const* d_in, const int* in_sizes, int n_in,
                              void* d_out, int out_size, void* d_ws, size_t ws_size,
                              hipStream_t stream) {
    const float* X = (const float*)d_in[0];   // [4,4096,4096] fp32
    const float* W = (const float*)d_in[1];   // [64,4096] fp32
    float* out = (float*)d_out;
    float* wsf = (float*)d_ws;

    const size_t need = 4ull * WS_BPACK + 2ull * 524288;  // slots + Bpack ~ 1.1 MB

    if (ws_size >= need) {
        unsigned short* Bpk = (unsigned short*)(wsf + WS_BPACK);
        moe_prep<<<(NEXP * HID + 255) / 256, 256, 0, stream>>>(W, Bpk, wsf);
        moe_fused<<<TOKS / 64, 512, 0, stream>>>(X, Bpk, out, wsf);
        moe_fix<<<256, 256, 0, stream>>>(X, W, out, wsf);
        moe_final<<<1, 64, 0, stream>>>(wsf, out);
    } else {
        double* Wd = (double*)d_ws;
        float* wsf2 = (float*)(Wd + NEXP * HID);
        moe_w_cvt<<<(NEXP * HID + 255) / 256, 256, 0, stream>>>(W, Wd);
        moe_init<<<1, 256, 0, stream>>>(wsf2, 128);
        moe_mono<<<TOKS / 64, 512, 0, stream>>>(X, Wd, out, wsf2);
        moe_final<<<1, 64, 0, stream>>>(wsf2, out);
    }
}

// Round 20
// 218.002 us; speedup vs baseline: 2.4653x; 1.1128x over previous
//
#include <hip/hip_runtime.h>
#include <hip/hip_bf16.h>

#define TOKS 16384
#define HID  4096
#define NEXP 64
#define EPS  1e-4f   // flag threshold; trunc-split logit err ~6e-6 -> 16x margin

// ===== ws layout (floats) =====
// [0..63] prob sums | [64..127] argmax counts | int@[128] flag count |
// ints [192..192+16384) flag list | [16576) Bpack (1 MB, bf16 hi/lo per (kt,nt))
#define WS_FLAGCNT  128
#define WS_FLAGLIST 192
#define WS_BPACK    16576

typedef __attribute__((ext_vector_type(8))) short short8_t;
typedef __attribute__((ext_vector_type(4))) float f32x4;

static __device__ __forceinline__ unsigned short f2bf_rn(float x) {
    unsigned u = __builtin_bit_cast(unsigned, x);
    u = (u + 0x7fffu + ((u >> 16) & 1u)) >> 16;
    return (unsigned short)u;
}
static __device__ __forceinline__ float bf2f(unsigned short h) {
    return __builtin_bit_cast(float, (unsigned)h << 16);
}
static __device__ __forceinline__ void gl2lds16(const void* g, void* l) {
    __builtin_amdgcn_global_load_lds(
        (const __attribute__((address_space(1))) unsigned int*)g,
        (__attribute__((address_space(3))) unsigned int*)l, 16, 0, 0);
}

// ---------- prep: W -> frag-packed bf16; (kt,nt) block = 2 KB: hi 1 KB | lo 1 KB ----------
// u16 index: (kt*4+nt)*1024 + plane*512 + lane*8 + j ; lane=(n&15)|(((k>>3)&3)<<4), j=k&7
__global__ void moe_prep(const float* __restrict__ W, unsigned short* __restrict__ Bpk,
                         float* __restrict__ wsf) {
    const int idx = blockIdx.x * blockDim.x + threadIdx.x;
    if (idx < 192) wsf[idx] = 0.0f;
    if (idx >= NEXP * HID) return;
    const int n = idx >> 12;
    const int k = idx & 4095;
    const float w = W[idx];
    const unsigned short hi = f2bf_rn(w);
    const unsigned short lo = f2bf_rn(w - bf2f(hi));
    const int kt   = k >> 5;
    const int nt   = n >> 4;
    const int lane = (n & 15) | (((k >> 3) & 3) << 4);
    const int j    = k & 7;
    const int dst  = (((kt << 2) + nt) << 10) + (lane << 3) + j;
    Bpk[dst]       = hi;
    Bpk[dst + 512] = lo;
}

// ---------- fused: 16-wave (4/SIMD) pipelined MFMA GEMM + softmax + bitonic top-8 ----------
// 256 blocks x 1024 thr (16 waves = 4/SIMD for latency hiding in the compute phase).
// Block: 64 tok x 64 exp, 64 K-steps of BK=64. Wave w = (mt=w&3, nt=w>>2): one 16x16
// output frag, acc = single f32x4. 4-deep LDS bufs, prefetch dist 2, 1 X + 1 B gl_lds
// per wave per stage, counted vmcnt(4), one s_barrier per step (R12-proven schedule).
__global__ __launch_bounds__(1024, 1)
void moe_fused(const float* __restrict__ X, const unsigned short* __restrict__ Bpk,
               float* __restrict__ out, float* __restrict__ wsf) {
    __shared__ __align__(16) char xbuf[4][16384];  // X: 64 rows x 256 B, chunk-XOR swz
    __shared__ __align__(16) char bbuf[4][16384];  // B: (ktl,nt) 2 KB blocks (hi|lo)
    float (*L)[68] = (float (*)[68])&xbuf[0][0];   // epilogue alias (17408 B)

    const int tid  = threadIdx.x;
    const int lane = tid & 63;
    const int w    = tid >> 6;                 // 0..15
    const int mt   = w & 3;                    // m-tile (16 tokens)
    const int nt   = w >> 2;                   // n-tile (16 experts)
    const int g    = lane >> 4;                // 0..3
    const int r    = lane & 15;                // token row within tile
    const int tok0 = blockIdx.x * 64;

    f32x4 acc = (f32x4){0.f, 0.f, 0.f, 0.f};

    // X staging: wave w stages rows w*4..w*4+3 (one 1 KB gl_lds). lane L -> row
    // w*4 + L/16, LDS chunk pos L&15 holds global chunk (L&15)^(row&15).
    const int srow  = (w << 2) + (lane >> 4);
    const int schk  = (lane & 15) ^ (srow & 15);
    const size_t xsrc = (size_t)(tok0 + srow) * HID + (schk << 2);
    const char* BpkB = (const char*)Bpk;

    // stage step ss into buffer bf: 1 X + 1 B gl_lds per wave (2 vmcnt events)
    #define STAGE(bf, ss)                                                              \
    {                                                                                  \
        gl2lds16(X + xsrc + ((ss) << 6), (void*)(&xbuf[bf][0] + (w << 10)));           \
        gl2lds16(BpkB + ((size_t)(ss) << 14) + (w << 10) + (lane << 4),                \
                 (void*)(&bbuf[bf][0] + (w << 10)));                                   \
    }

    STAGE(0, 0);
    STAGE(1, 1);

    for (int s = 0; s < 64; ++s) {
        const int cur = s & 3;
        const int ss = (s + 2 < 64) ? (s + 2) : 63;     // tail dups land in dead bufs
        STAGE((s + 2) & 3, ss);
        asm volatile("s_waitcnt vmcnt(4)" ::: "memory"); // drain stage(s); keep s+1,s+2
        __builtin_amdgcn_s_barrier();
        __builtin_amdgcn_sched_barrier(0);

        const char* ab = &xbuf[cur][0] + (((mt << 4) + r) << 8);
        const char* bb = &bbuf[cur][0];
        #pragma unroll
        for (int ktl = 0; ktl < 2; ++ktl) {
            const int cl = (ktl << 3) + (g << 1);        // global chunk of this k-slice
            const float4 a0 = *(const float4*)(ab + (((cl)     ^ r) << 4));
            const float4 a1 = *(const float4*)(ab + (((cl + 1) ^ r) << 4));
            const float xv[8] = {a0.x, a0.y, a0.z, a0.w, a1.x, a1.y, a1.z, a1.w};
            short8_t ah, al;
            #pragma unroll
            for (int j = 0; j < 8; ++j) {                // exact trunc split: x = hif+lof
                const unsigned u = __builtin_bit_cast(unsigned, xv[j]);
                ah[j] = (short)(u >> 16);
                const float hif = __builtin_bit_cast(float, u & 0xFFFF0000u);
                al[j] = (short)(__builtin_bit_cast(unsigned, xv[j] - hif) >> 16);
            }
            const char* bp = bb + (((ktl << 2) + nt) << 11) + (lane << 4);
            const short8_t bh = *(const short8_t*)bp;
            const short8_t bl = *(const short8_t*)(bp + 1024);
            acc = __builtin_amdgcn_mfma_f32_16x16x32_bf16(ah, bh, acc, 0, 0, 0);
            acc = __builtin_amdgcn_mfma_f32_16x16x32_bf16(al, bh, acc, 0, 0, 0);
            acc = __builtin_amdgcn_mfma_f32_16x16x32_bf16(ah, bl, acc, 0, 0, 0);
        }
    }
    asm volatile("s_waitcnt vmcnt(0)" ::: "memory");
    __syncthreads();

    // ---- logits -> L[token][expert] (aliases dead staging bufs) ----
    // C/D: col = lane&15 (expert within ntile), row = (lane>>4)*4 + reg (token)
    #pragma unroll
    for (int rr = 0; rr < 4; ++rr)
        L[(mt << 4) + (g << 2) + rr][(nt << 4) + r] = acc[rr];
    __syncthreads();

    // ---- epilogue: wave w handles tokens w*4 .. w*4+3; lane = expert ----
    float* outIdx = out;
    float* outW   = out + TOKS * 8;
    int* flagcnt  = (int*)wsf + WS_FLAGCNT;
    int* flaglist = (int*)wsf + WS_FLAGLIST;

    float rp = 0.f;
    #pragma unroll
    for (int tt = 0; tt < 4; ++tt) {
        const int tl = (w << 2) + tt;
        const float lg = L[tl][lane];

        // bitonic sort-64, descending by (value, then lower index first)
        float v = lg; int idx = lane;
        #pragma unroll
        for (int size = 2; size <= 64; size <<= 1) {
            #pragma unroll
            for (int str = size >> 1; str > 0; str >>= 1) {
                const float ov = __shfl_xor(v, str, 64);
                const int   oi = __shfl_xor(idx, str, 64);
                const bool pb = (ov > v) || (ov == v && oi < idx);
                const bool keepFirst = ((lane & str) == 0) == ((lane & size) == 0);
                if (pb == keepFirst) { v = ov; idx = oi; }
            }
        }

        const float m = __shfl(v, 0, 64);
        const float p = __expf(lg - m);
        float sdenom = p;
        #pragma unroll
        for (int o = 32; o; o >>= 1) sdenom += __shfl_xor(sdenom, o, 64);
        const float inv_s = 1.0f / sdenom;
        rp += p * inv_s;

        const float wkv = __expf(v - m) * inv_s;
        float d8 = (lane < 8) ? wkv : 0.f;
        #pragma unroll
        for (int o = 1; o < 8; o <<= 1) d8 += __shfl_xor(d8, o, 64);
        const float invd = 1.0f / (d8 + 1e-20f);
        const float nv = __shfl_down(v, 1, 64);
        const bool flg = __any(lane < 8 && (v - nv) < EPS);

        const int gtok = tok0 + tl;
        if (lane < 8) {
            outIdx[(size_t)gtok * 8 + lane] = (float)idx;
            outW[(size_t)gtok * 8 + lane]   = wkv * invd;
        }
        if (lane == 0) {
            atomicAdd(&wsf[NEXP + idx], 1.0f);
            if (flg) {
                const int pos = atomicAdd(flagcnt, 1);
                if (pos < TOKS) flaglist[pos] = gtok;
            }
        }
    }
    atomicAdd(&wsf[lane], rp);
    #undef STAGE
}

// ---------- exact fp64 redo for flagged tokens ----------
__global__ __launch_bounds__(256, 2)
void moe_fix(const float* __restrict__ X, const float* __restrict__ W,
             float* __restrict__ out, float* __restrict__ wsf) {
    __shared__ double red[256];
    const int tid = threadIdx.x;
    const int e   = tid & 63;
    const int kc  = tid >> 6;
    const int nf  = min(*((int*)wsf + WS_FLAGCNT), TOKS);
    const int* flaglist = (const int*)wsf + WS_FLAGLIST;
    float* outIdx = out;
    float* outW   = out + TOKS * 8;

    for (int fi = blockIdx.x; fi < nf; fi += gridDim.x) {
        const int tok = flaglist[fi];
        const float* xrow = X + (size_t)tok * HID + kc * 1024;
        const float* wrow = W + (size_t)e  * HID + kc * 1024;
        double part = 0.0;
        for (int j = 0; j < 1024; j += 4) {
            const float4 xv = *(const float4*)(xrow + j);
            const float4 wv = *(const float4*)(wrow + j);
            part = fma((double)xv.x, (double)wv.x, part);
            part = fma((double)xv.y, (double)wv.y, part);
            part = fma((double)xv.z, (double)wv.z, part);
            part = fma((double)xv.w, (double)wv.w, part);
        }
        red[tid] = part;
        __syncthreads();
        if (tid < 64) {
            const double lg = ((red[tid] + red[64 + tid]) + red[128 + tid]) + red[192 + tid];
            const float lgf = (float)lg;
            float m = lgf;
            #pragma unroll
            for (int o = 32; o; o >>= 1) m = fmaxf(m, __shfl_xor(m, o, 64));
            const float p = __expf(lgf - m);
            float s = p;
            #pragma unroll
            for (int o = 32; o; o >>= 1) s += __shfl_xor(s, o, 64);
            const float inv_s = 1.0f / s;

            double v = lg;
            double bw[8]; int ik[8];
            #pragma unroll
            for (int k = 0; k < 8; ++k) {
                double bv = v; int bi = tid;
                #pragma unroll
                for (int o = 32; o; o >>= 1) {
                    const double ov = __shfl_xor(bv, o, 64);
                    const int    oi = __shfl_xor(bi, o, 64);
                    if (ov > bv || (ov == bv && oi < bi)) { bv = ov; bi = oi; }
                }
                bw[k] = bv; ik[k] = bi;
                if (tid == bi) v = -1.0e300;
            }
            float wk[8]; float denom = 1e-20f;
            #pragma unroll
            for (int k = 0; k < 8; ++k) {
                wk[k] = __expf((float)bw[k] - m) * inv_s; denom += wk[k];
            }
            const float invd = 1.0f / denom;
            const size_t base = (size_t)tok * 8;
            const int oldtop = (int)outIdx[base];
            if (tid < 8) {
                outIdx[base + tid] = (float)ik[tid];
                outW[base + tid]   = wk[tid] * invd;
            }
            if (tid == 0 && ik[0] != oldtop) {
                atomicAdd(&wsf[NEXP + oldtop], -1.0f);
                atomicAdd(&wsf[NEXP + ik[0]],  1.0f);
            }
        }
        __syncthreads();
    }
}

__global__ void moe_final(const float* __restrict__ wsf, float* __restrict__ out) {
    const int e = threadIdx.x;  // 64 threads
    float v = wsf[e] * wsf[NEXP + e];
    #pragma unroll
    for (int o = 32; o; o >>= 1) v += __shfl_xor(v, o, 64);
    if (e == 0)
        out[2 * TOKS * 8] = v * (64.0f / ((float)TOKS * (float)TOKS));
}

// ===== fallback monolith (proven R2 path) for small ws =====
__global__ void moe_init(float* __restrict__ wsf, int n) {
    const int i = blockIdx.x * blockDim.x + threadIdx.x;
    if (i < n) wsf[i] = 0.0f;
}

__global__ void moe_w_cvt(const float* __restrict__ W, double* __restrict__ Wd) {
    const int i = blockIdx.x * blockDim.x + threadIdx.x;
    if (i < NEXP * HID) Wd[i] = (double)W[i];
}

__global__ __launch_bounds__(512, 2)
void moe_mono(const float* __restrict__ X, const double* __restrict__ Wd,
              float* __restrict__ out, float* __restrict__ wsf) {
    __shared__ double xs[64][66];
    __shared__ double L2[64][65];
    const int tid  = threadIdx.x;
    const int lane = tid & 63;
    const int wid  = __builtin_amdgcn_readfirstlane(tid >> 6);
    const int tok0 = blockIdx.x * 64;
    double acc[8] = {0., 0., 0., 0., 0., 0., 0., 0.};
    for (int h0 = 0; h0 < HID; h0 += 64) {
        #pragma unroll
        for (int i = 0; i < 8; ++i) {
            const int li = tid + i * 512;
            xs[li >> 6][li & 63] = (double)X[((size_t)(tok0 + (li >> 6)) << 12) + (h0 + (li & 63))];
        }
        __syncthreads();
        const double* wchunk = Wd + (((size_t)(wid << 3)) << 12) + h0;
        #pragma unroll 2
        for (int hh = 0; hh < 64; hh += 2) {
            const double2 xv = *(const double2*)&xs[lane][hh];
            #pragma unroll
            for (int e = 0; e < 8; ++e) {
                const double* wr = wchunk + (((size_t)e) << 12) + hh;
                acc[e] = fma(xv.x, wr[0], acc[e]);
                acc[e] = fma(xv.y, wr[1], acc[e]);
            }
        }
        __syncthreads();
    }
    #pragma unroll
    for (int e = 0; e < 8; ++e) L2[lane][(wid << 3) + e] = acc[e];
    __syncthreads();
    float* outIdx = out;
    float* outW   = out + (TOKS * 8);
    float rp = 0.0f;
    for (int tt = 0; tt < 8; ++tt) {
        const int t = (wid << 3) + tt;
        const double lg = L2[t][lane];
        const float lgf = (float)lg;
        float m = lgf;
        #pragma unroll
        for (int o = 32; o; o >>= 1) m = fmaxf(m, __shfl_xor(m, o, 64));
        const float p = __expf(lgf - m);
        float s = p;
        #pragma unroll
        for (int o = 32; o; o >>= 1) s += __shfl_xor(s, o, 64);
        const float inv_s = 1.0f / s;
        rp += p * inv_s;
        double v = lg;
        float wk[8]; int ik[8];
        #pragma unroll
        for (int k = 0; k < 8; ++k) {
            double bv = v; int bi = lane;
            #pragma unroll
            for (int o = 32; o; o >>= 1) {
                const double ov = __shfl_xor(bv, o, 64);
                const int    oi = __shfl_xor(bi, o, 64);
                if (ov > bv || (ov == bv && oi < bi)) { bv = ov; bi = oi; }
            }
            wk[k] = __expf((float)bv - m) * inv_s; ik[k] = bi;
            if (lane == bi) v = -1.0e300;
        }
        if (lane == 0) {
            const float denom = (((wk[0]+wk[1])+(wk[2]+wk[3])) +
                                 ((wk[4]+wk[5])+(wk[6]+wk[7]))) + 1e-20f;
            const float invd = 1.0f / denom;
            const size_t base = ((size_t)(tok0 + t)) << 3;
            #pragma unroll
            for (int k = 0; k < 8; ++k) {
                outIdx[base + k] = (float)ik[k];
                outW[base + k]   = wk[k] * invd;
            }
            atomicAdd(&wsf[NEXP + ik[0]], 1.0f);
        }
    }
    atomicAdd(&wsf[lane], rp);
}

extern "C" void kernel_launch(void* const* d_in, const int* in_sizes, int n_in,
                              void* d_out, int out_size, void* d_ws, size_t ws_size,
                              hipStream_t stream) {
    const float* X = (const float*)d_in[0];   // [4,4096,4096] fp32
    const float* W = (const float*)d_in[1];   // [64,4096] fp32
    float* out = (float*)d_out;
    float* wsf = (float*)d_ws;

    const size_t need = 4ull * WS_BPACK + 2ull * 524288;  // slots + Bpack ~ 1.1 MB

    if (ws_size >= need) {
        unsigned short* Bpk = (unsigned short*)(wsf + WS_BPACK);
        moe_prep<<<(NEXP * HID + 255) / 256, 256, 0, stream>>>(W, Bpk, wsf);
        moe_fused<<<TOKS / 64, 1024, 0, stream>>>(X, Bpk, out, wsf);
        moe_fix<<<256, 256, 0, stream>>>(X, W, out, wsf);
        moe_final<<<1, 64, 0, stream>>>(wsf, out);
    } else {
        double* Wd = (double*)d_ws;
        float* wsf2 = (float*)(Wd + NEXP * HID);
        moe_w_cvt<<<(NEXP * HID + 255) / 256, 256, 0, stream>>>(W, Wd);
        moe_init<<<1, 256, 0, stream>>>(wsf2, 128);
        moe_mono<<<TOKS / 64, 512, 0, stream>>>(X, Wd, out, wsf2);
        moe_final<<<1, 64, 0, stream>>>(wsf2, out);
    }
}

// Round 21
// 199.012 us; speedup vs baseline: 2.7005x; 1.0954x over previous
//
#include <hip/hip_runtime.h>
#include <hip/hip_bf16.h>

#define TOKS 16384
#define HID  4096
#define NEXP 64
#define EPS  1e-4f   // flag threshold; trunc-split logit err ~6e-6 -> 16x margin

// ===== ws layout (floats) =====
// [0..63] prob sums | [64..127] argmax counts | int@[128] flag count |
// ints [192..192+16384) flag list | [16576) Bpack (1 MB, bf16 hi/lo per (kt,nt))
#define WS_FLAGCNT  128
#define WS_FLAGLIST 192
#define WS_BPACK    16576

typedef __attribute__((ext_vector_type(8))) short short8_t;
typedef __attribute__((ext_vector_type(4))) float f32x4;

static __device__ __forceinline__ unsigned short f2bf_rn(float x) {
    unsigned u = __builtin_bit_cast(unsigned, x);
    u = (u + 0x7fffu + ((u >> 16) & 1u)) >> 16;
    return (unsigned short)u;
}
static __device__ __forceinline__ float bf2f(unsigned short h) {
    return __builtin_bit_cast(float, (unsigned)h << 16);
}
static __device__ __forceinline__ void gl2lds16(const void* g, void* l) {
    __builtin_amdgcn_global_load_lds(
        (const __attribute__((address_space(1))) unsigned int*)g,
        (__attribute__((address_space(3))) unsigned int*)l, 16, 0, 0);
}

// ---------- prep: W -> frag-packed bf16; (kt,nt) block = 2 KB: hi 1 KB | lo 1 KB ----------
// u16 index: (kt*4+nt)*1024 + plane*512 + lane*8 + j ; lane=(n&15)|(((k>>3)&3)<<4), j=k&7
__global__ void moe_prep(const float* __restrict__ W, unsigned short* __restrict__ Bpk,
                         float* __restrict__ wsf) {
    const int idx = blockIdx.x * blockDim.x + threadIdx.x;
    if (idx < 192) wsf[idx] = 0.0f;
    if (idx >= NEXP * HID) return;
    const int n = idx >> 12;
    const int k = idx & 4095;
    const float w = W[idx];
    const unsigned short hi = f2bf_rn(w);
    const unsigned short lo = f2bf_rn(w - bf2f(hi));
    const int kt   = k >> 5;
    const int nt   = n >> 4;
    const int lane = (n & 15) | (((k >> 3) & 3) << 4);
    const int j    = k & 7;
    const int dst  = (((kt << 2) + nt) << 10) + (lane << 3) + j;
    Bpk[dst]       = hi;
    Bpk[dst + 512] = lo;
}

// ---------- fused: PRODUCER/CONSUMER wave-specialized MFMA GEMM + epilogue ----------
// 256 blocks x 768 thr (12 waves): waves 8..11 = PRODUCERS (pure gl_lds loop, the
// R17-probe structure that measured 3.2 TB/s); waves 0..7 = CONSUMERS (R12 compute,
// ZERO VMEM instructions in the loop). 4-deep 128 KB LDS, one s_barrier per step.
// Producer iter s: issue stage(s+2), vmcnt(8) [stage s+1 drained, s+2 in flight],
// barrier. Consumer iter s: barrier, compute buf s&3. Writer (s+2)&3 vs reader s&3.
__global__ __launch_bounds__(768, 1)
void moe_fused(const float* __restrict__ X, const unsigned short* __restrict__ Bpk,
               float* __restrict__ out, float* __restrict__ wsf) {
    __shared__ __align__(16) char xbuf[4][16384];  // X: 64 rows x 256 B, src-XOR-swz
    __shared__ __align__(16) char bbuf[4][16384];  // B: (ktl,nt) 2 KB blocks (hi|lo)
    float (*L)[68] = (float (*)[68])&xbuf[0][0];   // epilogue alias (17408 B)

    const int tid  = threadIdx.x;
    const int lane = tid & 63;
    const int w    = tid >> 6;                 // 0..11
    const int tok0 = blockIdx.x * 64;

    f32x4 acc[2];
    acc[0] = (f32x4){0.f, 0.f, 0.f, 0.f};
    acc[1] = (f32x4){0.f, 0.f, 0.f, 0.f};

    if (w >= 8) {
        // ================= PRODUCER (probe-proven structure) =================
        const int p = w - 8;                   // 0..3
        size_t xsrc[4]; int xdst[4];
        #pragma unroll
        for (int j = 0; j < 4; ++j) {          // X instr i=p*4+j covers rows 4i..4i+3
            const int i  = (p << 2) + j;
            const int rg = (i << 2) + (lane >> 4);
            const int ck = (lane & 15) ^ (rg & 15);    // R12-proven src-XOR swizzle
            xsrc[j] = (size_t)(tok0 + rg) * HID + (ck << 2);
            xdst[j] = i << 10;
        }
        const char* BpkB = (const char*)Bpk;
        #define PSTAGE(bf, ss)                                                         \
        {                                                                              \
            const int k0_ = (ss) << 6;                                                 \
            _Pragma("unroll")                                                          \
            for (int j = 0; j < 4; ++j)                                                \
                gl2lds16(X + xsrc[j] + k0_, (void*)(&xbuf[bf][0] + xdst[j]));          \
            _Pragma("unroll")                                                          \
            for (int j = 0; j < 4; ++j) {                                              \
                const int c1k = (p << 2) + j;                                          \
                gl2lds16(BpkB + ((size_t)(ss) << 14) + (c1k << 10) + (lane << 4),      \
                         (void*)(&bbuf[bf][0] + (c1k << 10)));                         \
            }                                                                          \
        }
        PSTAGE(0, 0);
        PSTAGE(1, 1);
        for (int s = 0; s < 64; ++s) {
            const int ss = (s + 2 < 64) ? (s + 2) : 63;   // tail dups land in dead bufs
            PSTAGE((s + 2) & 3, ss);
            asm volatile("s_waitcnt vmcnt(8)" ::: "memory");  // stage s+1 drained
            __builtin_amdgcn_s_barrier();
        }
        asm volatile("s_waitcnt vmcnt(0)" ::: "memory");
        #undef PSTAGE
    } else {
        // ================= CONSUMER (R12-proven compute, no VMEM) =================
        const int mt = w & 3;                  // m-tile (16 tokens)
        const int nh = w >> 2;                 // n-half (2 ntiles)
        const int g  = lane >> 4;
        const int tr = (mt << 4) + (lane & 15);
        const int rsw = lane & 15;
        for (int s = 0; s < 64; ++s) {
            __builtin_amdgcn_s_barrier();
            __builtin_amdgcn_sched_barrier(0);
            const int cur = s & 3;
            const char* ab = &xbuf[cur][0] + (tr << 8);
            const char* bb = &bbuf[cur][0];
            #pragma unroll
            for (int ktl = 0; ktl < 2; ++ktl) {
                const int cl = (ktl << 3) + (g << 1);
                const float4 a0 = *(const float4*)(ab + ((cl ^ rsw) << 4));
                const float4 a1 = *(const float4*)(ab + (((cl + 1) ^ rsw) << 4));
                const float xv[8] = {a0.x, a0.y, a0.z, a0.w, a1.x, a1.y, a1.z, a1.w};
                short8_t ah, al;
                #pragma unroll
                for (int j = 0; j < 8; ++j) {  // exact trunc split: x = hif + lof
                    const unsigned u = __builtin_bit_cast(unsigned, xv[j]);
                    ah[j] = (short)(u >> 16);
                    const float hif = __builtin_bit_cast(float, u & 0xFFFF0000u);
                    al[j] = (short)(__builtin_bit_cast(unsigned, xv[j] - hif) >> 16);
                }
                #pragma unroll
                for (int ntl = 0; ntl < 2; ++ntl) {
                    const char* bp = bb + (((ktl << 2) + (nh << 1) + ntl) << 11) + (lane << 4);
                    const short8_t bh = *(const short8_t*)bp;
                    const short8_t bl = *(const short8_t*)(bp + 1024);
                    acc[ntl] = __builtin_amdgcn_mfma_f32_16x16x32_bf16(ah, bh, acc[ntl], 0, 0, 0);
                    acc[ntl] = __builtin_amdgcn_mfma_f32_16x16x32_bf16(al, bh, acc[ntl], 0, 0, 0);
                    acc[ntl] = __builtin_amdgcn_mfma_f32_16x16x32_bf16(ah, bl, acc[ntl], 0, 0, 0);
                }
            }
            __builtin_amdgcn_sched_barrier(0);
        }
    }
    __syncthreads();   // all 12 waves; drains producer LDS writes

    // ---- logits -> L[token][expert] (L aliases xbuf; consumers only) ----
    if (w < 8) {
        const int mt = w & 3, nh = w >> 2, g = lane >> 4;
        #pragma unroll
        for (int ntl = 0; ntl < 2; ++ntl)
            #pragma unroll
            for (int rr = 0; rr < 4; ++rr)
                L[(mt << 4) + (g << 2) + rr][(nh << 5) + (ntl << 4) + (lane & 15)] = acc[ntl][rr];
    }
    __syncthreads();

    // ---- epilogue: consumer wave w handles tokens w*8 .. w*8+7; lane = expert ----
    float* outIdx = out;
    float* outW   = out + TOKS * 8;
    int* flagcnt  = (int*)wsf + WS_FLAGCNT;
    int* flaglist = (int*)wsf + WS_FLAGLIST;

    if (w < 8) {
        float rp = 0.f;
        #pragma unroll
        for (int tt = 0; tt < 8; ++tt) {
            const int tl = (w << 3) + tt;
            const float lg = L[tl][lane];

            // bitonic sort-64, descending by (value, then lower index first)
            float v = lg; int idx = lane;
            #pragma unroll
            for (int size = 2; size <= 64; size <<= 1) {
                #pragma unroll
                for (int str = size >> 1; str > 0; str >>= 1) {
                    const float ov = __shfl_xor(v, str, 64);
                    const int   oi = __shfl_xor(idx, str, 64);
                    const bool pb = (ov > v) || (ov == v && oi < idx);
                    const bool keepFirst = ((lane & str) == 0) == ((lane & size) == 0);
                    if (pb == keepFirst) { v = ov; idx = oi; }
                }
            }

            const float m = __shfl(v, 0, 64);
            const float p = __expf(lg - m);
            float sdenom = p;
            #pragma unroll
            for (int o = 32; o; o >>= 1) sdenom += __shfl_xor(sdenom, o, 64);
            const float inv_s = 1.0f / sdenom;
            rp += p * inv_s;

            const float wkv = __expf(v - m) * inv_s;
            float d8 = (lane < 8) ? wkv : 0.f;
            #pragma unroll
            for (int o = 1; o < 8; o <<= 1) d8 += __shfl_xor(d8, o, 64);
            const float invd = 1.0f / (d8 + 1e-20f);
            const float nv = __shfl_down(v, 1, 64);
            const bool flg = __any(lane < 8 && (v - nv) < EPS);

            const int gtok = tok0 + tl;
            if (lane < 8) {
                outIdx[(size_t)gtok * 8 + lane] = (float)idx;
                outW[(size_t)gtok * 8 + lane]   = wkv * invd;
            }
            if (lane == 0) {
                atomicAdd(&wsf[NEXP + idx], 1.0f);
                if (flg) {
                    const int pos = atomicAdd(flagcnt, 1);
                    if (pos < TOKS) flaglist[pos] = gtok;
                }
            }
        }
        atomicAdd(&wsf[lane], rp);
    }
}

// ---------- exact fp64 redo for flagged tokens ----------
__global__ __launch_bounds__(256, 2)
void moe_fix(const float* __restrict__ X, const float* __restrict__ W,
             float* __restrict__ out, float* __restrict__ wsf) {
    __shared__ double red[256];
    const int tid = threadIdx.x;
    const int e   = tid & 63;
    const int kc  = tid >> 6;
    const int nf  = min(*((int*)wsf + WS_FLAGCNT), TOKS);
    const int* flaglist = (const int*)wsf + WS_FLAGLIST;
    float* outIdx = out;
    float* outW   = out + TOKS * 8;

    for (int fi = blockIdx.x; fi < nf; fi += gridDim.x) {
        const int tok = flaglist[fi];
        const float* xrow = X + (size_t)tok * HID + kc * 1024;
        const float* wrow = W + (size_t)e  * HID + kc * 1024;
        double part = 0.0;
        for (int j = 0; j < 1024; j += 4) {
            const float4 xv = *(const float4*)(xrow + j);
            const float4 wv = *(const float4*)(wrow + j);
            part = fma((double)xv.x, (double)wv.x, part);
            part = fma((double)xv.y, (double)wv.y, part);
            part = fma((double)xv.z, (double)wv.z, part);
            part = fma((double)xv.w, (double)wv.w, part);
        }
        red[tid] = part;
        __syncthreads();
        if (tid < 64) {
            const double lg = ((red[tid] + red[64 + tid]) + red[128 + tid]) + red[192 + tid];
            const float lgf = (float)lg;
            float m = lgf;
            #pragma unroll
            for (int o = 32; o; o >>= 1) m = fmaxf(m, __shfl_xor(m, o, 64));
            const float p = __expf(lgf - m);
            float s = p;
            #pragma unroll
            for (int o = 32; o; o >>= 1) s += __shfl_xor(s, o, 64);
            const float inv_s = 1.0f / s;

            double v = lg;
            double bw[8]; int ik[8];
            #pragma unroll
            for (int k = 0; k < 8; ++k) {
                double bv = v; int bi = tid;
                #pragma unroll
                for (int o = 32; o; o >>= 1) {
                    const double ov = __shfl_xor(bv, o, 64);
                    const int    oi = __shfl_xor(bi, o, 64);
                    if (ov > bv || (ov == bv && oi < bi)) { bv = ov; bi = oi; }
                }
                bw[k] = bv; ik[k] = bi;
                if (tid == bi) v = -1.0e300;
            }
            float wk[8]; float denom = 1e-20f;
            #pragma unroll
            for (int k = 0; k < 8; ++k) {
                wk[k] = __expf((float)bw[k] - m) * inv_s; denom += wk[k];
            }
            const float invd = 1.0f / denom;
            const size_t base = (size_t)tok * 8;
            const int oldtop = (int)outIdx[base];
            if (tid < 8) {
                outIdx[base + tid] = (float)ik[tid];
                outW[base + tid]   = wk[tid] * invd;
            }
            if (tid == 0 && ik[0] != oldtop) {
                atomicAdd(&wsf[NEXP + oldtop], -1.0f);
                atomicAdd(&wsf[NEXP + ik[0]],  1.0f);
            }
        }
        __syncthreads();
    }
}

__global__ void moe_final(const float* __restrict__ wsf, float* __restrict__ out) {
    const int e = threadIdx.x;  // 64 threads
    float v = wsf[e] * wsf[NEXP + e];
    #pragma unroll
    for (int o = 32; o; o >>= 1) v += __shfl_xor(v, o, 64);
    if (e == 0)
        out[2 * TOKS * 8] = v * (64.0f / ((float)TOKS * (float)TOKS));
}

// ===== fallback monolith (proven R2 path) for small ws =====
__global__ void moe_init(float* __restrict__ wsf, int n) {
    const int i = blockIdx.x * blockDim.x + threadIdx.x;
    if (i < n) wsf[i] = 0.0f;
}

__global__ void moe_w_cvt(const float* __restrict__ W, double* __restrict__ Wd) {
    const int i = blockIdx.x * blockDim.x + threadIdx.x;
    if (i < NEXP * HID) Wd[i] = (double)W[i];
}

__global__ __launch_bounds__(512, 2)
void moe_mono(const float* __restrict__ X, const double* __restrict__ Wd,
              float* __restrict__ out, float* __restrict__ wsf) {
    __shared__ double xs[64][66];
    __shared__ double L2[64][65];
    const int tid  = threadIdx.x;
    const int lane = tid & 63;
    const int wid  = __builtin_amdgcn_readfirstlane(tid >> 6);
    const int tok0 = blockIdx.x * 64;
    double acc[8] = {0., 0., 0., 0., 0., 0., 0., 0.};
    for (int h0 = 0; h0 < HID; h0 += 64) {
        #pragma unroll
        for (int i = 0; i < 8; ++i) {
            const int li = tid + i * 512;
            xs[li >> 6][li & 63] = (double)X[((size_t)(tok0 + (li >> 6)) << 12) + (h0 + (li & 63))];
        }
        __syncthreads();
        const double* wchunk = Wd + (((size_t)(wid << 3)) << 12) + h0;
        #pragma unroll 2
        for (int hh = 0; hh < 64; hh += 2) {
            const double2 xv = *(const double2*)&xs[lane][hh];
            #pragma unroll
            for (int e = 0; e < 8; ++e) {
                const double* wr = wchunk + (((size_t)e) << 12) + hh;
                acc[e] = fma(xv.x, wr[0], acc[e]);
                acc[e] = fma(xv.y, wr[1], acc[e]);
            }
        }
        __syncthreads();
    }
    #pragma unroll
    for (int e = 0; e < 8; ++e) L2[lane][(wid << 3) + e] = acc[e];
    __syncthreads();
    float* outIdx = out;
    float* outW   = out + (TOKS * 8);
    float rp = 0.0f;
    for (int tt = 0; tt < 8; ++tt) {
        const int t = (wid << 3) + tt;
        const double lg = L2[t][lane];
        const float lgf = (float)lg;
        float m = lgf;
        #pragma unroll
        for (int o = 32; o; o >>= 1) m = fmaxf(m, __shfl_xor(m, o, 64));
        const float p = __expf(lgf - m);
        float s = p;
        #pragma unroll
        for (int o = 32; o; o >>= 1) s += __shfl_xor(s, o, 64);
        const float inv_s = 1.0f / s;
        rp += p * inv_s;
        double v = lg;
        float wk[8]; int ik[8];
        #pragma unroll
        for (int k = 0; k < 8; ++k) {
            double bv = v; int bi = lane;
            #pragma unroll
            for (int o = 32; o; o >>= 1) {
                const double ov = __shfl_xor(bv, o, 64);
                const int    oi = __shfl_xor(bi, o, 64);
                if (ov > bv || (ov == bv && oi < bi)) { bv = ov; bi = oi; }
            }
            wk[k] = __expf((float)bv - m) * inv_s; ik[k] = bi;
            if (lane == bi) v = -1.0e300;
        }
        if (lane == 0) {
            const float denom = (((wk[0]+wk[1])+(wk[2]+wk[3])) +
                                 ((wk[4]+wk[5])+(wk[6]+wk[7]))) + 1e-20f;
            const float invd = 1.0f / denom;
            const size_t base = ((size_t)(tok0 + t)) << 3;
            #pragma unroll
            for (int k = 0; k < 8; ++k) {
                outIdx[base + k] = (float)ik[k];
                outW[base + k]   = wk[k] * invd;
            }
            atomicAdd(&wsf[NEXP + ik[0]], 1.0f);
        }
    }
    atomicAdd(&wsf[lane], rp);
}

extern "C" void kernel_launch(void* const* d_in, const int* in_sizes, int n_in,
                              void* d_out, int out_size, void* d_ws, size_t ws_size,
                              hipStream_t stream) {
    const float* X = (const float*)d_in[0];   // [4,4096,4096] fp32
    const float* W = (const float*)d_in[1];   // [64,4096] fp32
    float* out = (float*)d_out;
    float* wsf = (float*)d_ws;

    const size_t need = 4ull * WS_BPACK + 2ull * 524288;  // slots + Bpack ~ 1.1 MB

    if (ws_size >= need) {
        unsigned short* Bpk = (unsigned short*)(wsf + WS_BPACK);
        moe_prep<<<(NEXP * HID + 255) / 256, 256, 0, stream>>>(W, Bpk, wsf);
        moe_fused<<<TOKS / 64, 768, 0, stream>>>(X, Bpk, out, wsf);
        moe_fix<<<256, 256, 0, stream>>>(X, W, out, wsf);
        moe_final<<<1, 64, 0, stream>>>(wsf, out);
    } else {
        double* Wd = (double*)d_ws;
        float* wsf2 = (float*)(Wd + NEXP * HID);
        moe_w_cvt<<<(NEXP * HID + 255) / 256, 256, 0, stream>>>(W, Wd);
        moe_init<<<1, 256, 0, stream>>>(wsf2, 128);
        moe_mono<<<TOKS / 64, 512, 0, stream>>>(X, Wd, out, wsf2);
        moe_final<<<1, 64, 0, stream>>>(wsf2, out);
    }
}